// Round 3
// baseline (99.391 us; speedup 1.0000x reference)
//
#include <hip/hip_runtime.h>

// Problem constants (from reference setup_inputs):
//   B=4, N=8192, C=256, NEIGHBOR_NUM=4, POOLING_RATE=4 -> P = N/4 = 2048
// Outputs (concatenated flat in d_out):
//   vertices_pool    (B, P, 3)   float32
//   feature_map_pool (B, P, C)   float32
//
// Reference semantics: for each query n, neighbors = the 4 SMALLEST indices m
// with dist2(n,m) <= radius^2 (self forced via zeroed diagonal), padded with
// the first hit. Only the 2048 sampled queries are computed.
//
// R2 -> R3: R2 kernel ~22us, still latency-chain-bound. R1's VGPR_Count=16
// showed the compiler serializes loads when compute is interleaved. Fix:
//   - CH=16 (1024 candidates per batch, max 8 serial iterations)
//   - explicit load->arrays, THEN compute (forces all loads in flight)
//   - software prefetch: batch i+1 loads issue before batch i ballots
//   - batch-0 loads issue before the query-point dependent chain

#define BB 4
#define NN 8192
#define CC 256
#define PP 2048
#define KK 4
#define CH 16                 // 64-candidate chunks per batch
#define BATCH (64 * CH)       // 1024 candidates per batch
#define NBATCH (NN / BATCH)   // 8 batches

__global__ __launch_bounds__(256) void pool_layer_kernel(
    const float* __restrict__ vertices,   // (B, N, 3)
    const float* __restrict__ feat,       // (B, N, C)
    const int*   __restrict__ radius_p,   // (1,)
    const int*   __restrict__ sample_idx, // (P,)
    float* __restrict__ out_v,            // (B, P, 3)
    float* __restrict__ out_f)            // (B, P, C)
{
    const int wave = threadIdx.x >> 6;
    const int lane = threadIdx.x & 63;
    const int q    = blockIdx.x * 4 + wave;    // query id in [0, B*P)
    const int b    = q >> 11;                  // q / P   (P = 2048)
    const int i    = q & (PP - 1);             // q % P
    const float* vb = vertices + (size_t)b * NN * 3;

    // ---- issue batch-0 candidate loads FIRST (independent of n) ----
    float px[CH], py[CH], pz[CH];
    #pragma unroll
    for (int c = 0; c < CH; ++c) {
        const int m = c * 64 + lane;
        px[c] = vb[m * 3 + 0];
        py[c] = vb[m * 3 + 1];
        pz[c] = vb[m * 3 + 2];
    }

    // ---- query point chain (overlaps batch-0 load latency) ----
    const int n = sample_idx[i];
    const float xn0 = vb[n * 3 + 0];
    const float xn1 = vb[n * 3 + 1];
    const float xn2 = vb[n * 3 + 2];
    // Reference's exact fp32 order, FMA contraction blocked via _rn intrinsics:
    const float sqn = __fadd_rn(__fadd_rn(__fmul_rn(xn0, xn0),
                                          __fmul_rn(xn1, xn1)),
                                __fmul_rn(xn2, xn2));
    const int   r  = radius_p[0];
    const float r2 = (float)(r * r);

    // vertices_pool gather (lanes 0..2 write x,y,z)
    if (lane < 3) {
        out_v[((size_t)b * PP + i) * 3 + lane] = vb[n * 3 + lane];
    }

    // ---- pipelined scan: prefetch batch bat+1, then process batch bat ----
    int cand[KK];
    int cnt = 0;
    for (int bat = 0; bat < NBATCH && cnt < KK; ++bat) {
        // prefetch next batch (clamped; redundant re-read on last batch is harmless)
        const int nb = (bat + 1 < NBATCH) ? (bat + 1) : bat;
        float nx[CH], ny[CH], nz[CH];
        #pragma unroll
        for (int c = 0; c < CH; ++c) {
            const int m = nb * BATCH + c * 64 + lane;
            nx[c] = vb[m * 3 + 0];
            ny[c] = vb[m * 3 + 1];
            nz[c] = vb[m * 3 + 2];
        }

        // process current batch from registers
        const int base = bat * BATCH;
        unsigned long long masks[CH];
        #pragma unroll
        for (int c = 0; c < CH; ++c) {
            const int m = base + c * 64 + lane;
            const float x0 = px[c], x1 = py[c], x2 = pz[c];
            const float sqm = __fadd_rn(__fadd_rn(__fmul_rn(x0, x0),
                                                  __fmul_rn(x1, x1)),
                                        __fmul_rn(x2, x2));
            const float dot = __fadd_rn(__fadd_rn(__fmul_rn(xn0, x0),
                                                  __fmul_rn(xn1, x1)),
                                        __fmul_rn(xn2, x2));
            const float dist = __fadd_rn(__fadd_rn(__fmul_rn(-2.0f, dot), sqn), sqm);
            masks[c] = __ballot((m == n) || !(dist > r2));
        }
        #pragma unroll
        for (int c = 0; c < CH; ++c) {
            unsigned long long mask = masks[c];  // wave-uniform
            while (mask && cnt < KK) {
                const int l = __ffsll(mask) - 1;
                cand[cnt++] = base + c * 64 + l;
                mask &= (mask - 1);
            }
        }

        // rotate prefetched batch into current
        #pragma unroll
        for (int c = 0; c < CH; ++c) { px[c] = nx[c]; py[c] = ny[c]; pz[c] = nz[c]; }
    }
    // cnt >= 1 always (self-hit). Pad with first hit per reference.
    for (int j = cnt; j < KK; ++j) cand[j] = cand[0];

    // ---- max-pool 4 feature rows (64 lanes x float4 = one 1KB row each) ----
    const float4* f0 = (const float4*)(feat + ((size_t)b * NN + cand[0]) * CC);
    const float4* f1 = (const float4*)(feat + ((size_t)b * NN + cand[1]) * CC);
    const float4* f2 = (const float4*)(feat + ((size_t)b * NN + cand[2]) * CC);
    const float4* f3 = (const float4*)(feat + ((size_t)b * NN + cand[3]) * CC);
    const float4 a0 = f0[lane];
    const float4 a1 = f1[lane];
    const float4 a2 = f2[lane];
    const float4 a3 = f3[lane];
    float4 o;
    o.x = fmaxf(fmaxf(a0.x, a1.x), fmaxf(a2.x, a3.x));
    o.y = fmaxf(fmaxf(a0.y, a1.y), fmaxf(a2.y, a3.y));
    o.z = fmaxf(fmaxf(a0.z, a1.z), fmaxf(a2.z, a3.z));
    o.w = fmaxf(fmaxf(a0.w, a1.w), fmaxf(a2.w, a3.w));
    ((float4*)(out_f + ((size_t)b * PP + i) * CC))[lane] = o;
}

extern "C" void kernel_launch(void* const* d_in, const int* in_sizes, int n_in,
                              void* d_out, int out_size, void* d_ws, size_t ws_size,
                              hipStream_t stream) {
    const float* vertices   = (const float*)d_in[0]; // (B,N,3) fp32
    const float* feat       = (const float*)d_in[1]; // (B,N,C) fp32
    const int*   radius_p   = (const int*)d_in[2];   // scalar int
    const int*   sample_idx = (const int*)d_in[3];   // (P,) int32

    float* out_v = (float*)d_out;                    // (B,P,3)
    float* out_f = out_v + (size_t)BB * PP * 3;      // (B,P,C)

    const int queries = BB * PP;                     // 8192 waves
    dim3 grid(queries / 4), block(256);              // 4 waves/block
    pool_layer_kernel<<<grid, block, 0, stream>>>(
        vertices, feat, radius_p, sample_idx, out_v, out_f);
}